// Round 1
// baseline (271.925 us; speedup 1.0000x reference)
//
#include <hip/hip_runtime.h>

// Fused LSTM (B=4096, T=256, I=128, H=64) + output projection (O=10).
// 256 WGs x 256 threads; WG owns 16 batch rows; wave q owns interleaved gate
// slice {64*nt + 16*q + col} so i/f/g/o for one (b,j) land in one lane.
// Weights live in VGPRs (bf16 fragments). x staged per-step into LDS (bf16,
// double-buffered, swizzled). One raw s_barrier per step (lgkmcnt only) so
// x prefetch loads stay in flight across steps. fp32 c/h carried in regs.

typedef __attribute__((ext_vector_type(8))) short bf16x8;
typedef __attribute__((ext_vector_type(4))) float f32x4;

#define T_STEPS 256

__device__ __forceinline__ short f2bf(float f) {
    unsigned u = __float_as_uint(f);
    u += 0x7FFFu + ((u >> 16) & 1u);   // round-to-nearest-even
    return (short)(u >> 16);
}

__device__ __forceinline__ float sigm(float x) { return 1.0f / (1.0f + __expf(-x)); }
__device__ __forceinline__ float tanh_f(float x) { return 1.0f - 2.0f / (__expf(2.0f * x) + 1.0f); }

#define MF(A, Bf, C) (C) = __builtin_amdgcn_mfma_f32_16x16x32_bf16((A), (Bf), (C), 0, 0, 0)

__global__ __launch_bounds__(256, 1) void lstm_fused_kernel(
    const float* __restrict__ x,
    const float* __restrict__ W_ih,
    const float* __restrict__ W_hh,
    const float* __restrict__ b_ih,
    const float* __restrict__ b_hh,
    const float* __restrict__ W_out,
    const float* __restrict__ b_out,
    float* __restrict__ out)
{
    // [0,8192): xf double buffer (2 x 4KB, bf16 A-fragments of x-tile)
    // [8192,12288): hBuf double buffer (2 x 2KB, bf16 h)
    // [12288,16384): hf (final h, fp32)
    __shared__ __align__(16) char smem[16384];

    const int tid  = threadIdx.x;
    const int lane = tid & 63;
    const int q    = tid >> 6;        // wave id = interleaved gate slice
    const int l15  = lane & 15;
    const int l4   = lane >> 4;
    const int b0   = blockIdx.x * 16;

    // ---------------- weight fragments (held in VGPRs all kernel) ----------
    // B-frag for n-tile nt: col l15 -> gate row = 64*nt + 16*q + l15
    // k index within K-slice: 32*ks + 8*l4 + j  (same formula for A side)
    bf16x8 Bih[4][4];
    bf16x8 Bhh[4][2];
    f32x4  biasC[4];
#pragma unroll
    for (int nt = 0; nt < 4; ++nt) {
        const int row = nt * 64 + q * 16 + l15;
#pragma unroll
        for (int ks = 0; ks < 4; ++ks) {
            const float* p = W_ih + row * 128 + ks * 32 + l4 * 8;
            f32x4 a = *(const f32x4*)p;
            f32x4 b = *(const f32x4*)(p + 4);
            bf16x8 w;
#pragma unroll
            for (int j = 0; j < 4; ++j) { w[j] = f2bf(a[j]); w[4 + j] = f2bf(b[j]); }
            Bih[nt][ks] = w;
        }
#pragma unroll
        for (int ks = 0; ks < 2; ++ks) {
            const float* p = W_hh + row * 64 + ks * 32 + l4 * 8;
            f32x4 a = *(const f32x4*)p;
            f32x4 b = *(const f32x4*)(p + 4);
            bf16x8 w;
#pragma unroll
            for (int j = 0; j < 4; ++j) { w[j] = f2bf(a[j]); w[4 + j] = f2bf(b[j]); }
            Bhh[nt][ks] = w;
        }
        const float bb = b_ih[row] + b_hh[row];
        biasC[nt] = (f32x4){bb, bb, bb, bb};
    }

    // ---------------- staging maps ----------------
    // thread (sb = tid>>4, sc = tid&15) loads x[b0+sb][t][8*sc .. +8] (32B,
    // coalesced: 16 threads cover one 512B row), converts to bf16, writes one
    // 16B chunk = exactly one lane's A-fragment slot.
    const int sc  = tid & 15;
    const int sb  = tid >> 4;
    const int sks = sc >> 2;
    const int schunk = ((sc & 3) << 4) | sb;
    const int xf_wr  = (((sks * 64 + schunk) * 16) ^ ((sks & 3) << 6));
    const float* xrow = x + (size_t)(b0 + sb) * T_STEPS * 128 + sc * 8;

    int xf_rd[4];
#pragma unroll
    for (int ks = 0; ks < 4; ++ks)
        xf_rd[ks] = (((ks * 64 + lane) * 16) ^ ((ks & 3) << 6));

    int hb_wr[4];
#pragma unroll
    for (int r = 0; r < 4; ++r) {
        const int b = l4 * 4 + r;           // batch row (C-layout: row=(l>>4)*4+reg)
        const int j = q * 16 + l15;         // hidden index
        hb_wr[r] = ((b * 128 + j * 2) ^ ((b & 7) << 4));
    }
    int hb_rd[2];
#pragma unroll
    for (int ks = 0; ks < 2; ++ks)
        hb_rd[ks] = ((l15 * 128 + ks * 64 + l4 * 16) ^ ((l15 & 7) << 4));

    // ---------------- prologue: stage t=0, zero hBuf0 ----------------
    {
        f32x4 a = *(const f32x4*)(xrow);
        f32x4 b = *(const f32x4*)(xrow + 4);
        bf16x8 xb;
#pragma unroll
        for (int j = 0; j < 4; ++j) { xb[j] = f2bf(a[j]); xb[4 + j] = f2bf(b[j]); }
        *(bf16x8*)(smem + xf_wr) = xb;               // xf buffer 0
    }
    ((unsigned long long*)(smem + 8192))[tid] = 0ull; // zero hBuf0 (2KB)

    asm volatile("s_waitcnt lgkmcnt(0)" ::: "memory");
    __builtin_amdgcn_s_barrier();

    // prefetch x(t=1) and x(t=2)
    f32x4 PA0 = *(const f32x4*)(xrow + 128);
    f32x4 PA1 = *(const f32x4*)(xrow + 132);
    f32x4 PB0 = *(const f32x4*)(xrow + 256);
    f32x4 PB1 = *(const f32x4*)(xrow + 260);

    float c[4]  = {0.f, 0.f, 0.f, 0.f};
    float hl[4] = {0.f, 0.f, 0.f, 0.f};

#define STEP(tcur, RD, PX0, PX1)                                               \
  {                                                                            \
    const char* xfb = smem + (RD) * 4096;                                      \
    char*       xfw = smem + (((RD) ^ 1)) * 4096;                              \
    const char* hbR = smem + 8192 + (RD) * 2048;                               \
    char*       hbW = smem + 8192 + (((RD) ^ 1)) * 2048;                       \
    bf16x8 Ax0 = *(const bf16x8*)(xfb + xf_rd[0]);                             \
    bf16x8 Ax1 = *(const bf16x8*)(xfb + xf_rd[1]);                             \
    bf16x8 Ax2 = *(const bf16x8*)(xfb + xf_rd[2]);                             \
    bf16x8 Ax3 = *(const bf16x8*)(xfb + xf_rd[3]);                             \
    bf16x8 Ah0 = *(const bf16x8*)(hbR + hb_rd[0]);                             \
    bf16x8 Ah1 = *(const bf16x8*)(hbR + hb_rd[1]);                             \
    f32x4 acc0 = biasC[0], acc1 = biasC[1], acc2 = biasC[2], acc3 = biasC[3];  \
    MF(Ax0, Bih[0][0], acc0); MF(Ax0, Bih[1][0], acc1);                        \
    MF(Ax0, Bih[2][0], acc2); MF(Ax0, Bih[3][0], acc3);                        \
    MF(Ax1, Bih[0][1], acc0); MF(Ax1, Bih[1][1], acc1);                        \
    MF(Ax1, Bih[2][1], acc2); MF(Ax1, Bih[3][1], acc3);                        \
    MF(Ax2, Bih[0][2], acc0); MF(Ax2, Bih[1][2], acc1);                        \
    MF(Ax2, Bih[2][2], acc2); MF(Ax2, Bih[3][2], acc3);                        \
    MF(Ax3, Bih[0][3], acc0); MF(Ax3, Bih[1][3], acc1);                        \
    MF(Ax3, Bih[2][3], acc2); MF(Ax3, Bih[3][3], acc3);                        \
    MF(Ah0, Bhh[0][0], acc0); MF(Ah0, Bhh[1][0], acc1);                        \
    MF(Ah0, Bhh[2][0], acc2); MF(Ah0, Bhh[3][0], acc3);                        \
    MF(Ah1, Bhh[0][1], acc0); MF(Ah1, Bhh[1][1], acc1);                        \
    MF(Ah1, Bhh[2][1], acc2); MF(Ah1, Bhh[3][1], acc3);                        \
    /* stage x(t+1) (regs -> bf16 -> LDS), then issue loads for x(t+3) */      \
    {                                                                          \
      bf16x8 xb;                                                               \
      _Pragma("unroll")                                                        \
      for (int j = 0; j < 4; ++j) { xb[j] = f2bf((PX0)[j]); xb[4 + j] = f2bf((PX1)[j]); } \
      *(bf16x8*)(xfw + xf_wr) = xb;                                            \
    }                                                                          \
    {                                                                          \
      int tc = (tcur) + 3; if (tc > 255) tc = 255;                             \
      (PX0) = *(const f32x4*)(xrow + (size_t)tc * 128);                        \
      (PX1) = *(const f32x4*)(xrow + (size_t)tc * 128 + 4);                    \
    }                                                                          \
    /* lane-local gate nonlinearities + c/h update (nt: 0=i,1=f,2=g,3=o) */    \
    _Pragma("unroll")                                                          \
    for (int r = 0; r < 4; ++r) {                                              \
      float iv = sigm(acc0[r]);                                                \
      float fv = sigm(acc1[r]);                                                \
      float gv = tanh_f(acc2[r]);                                              \
      float ov = sigm(acc3[r]);                                                \
      float cc = fv * c[r] + iv * gv;                                          \
      c[r] = cc;                                                               \
      float hv = ov * tanh_f(cc);                                              \
      hl[r] = hv;                                                              \
      *(short*)(hbW + hb_wr[r]) = f2bf(hv);                                    \
    }                                                                          \
    asm volatile("s_waitcnt lgkmcnt(0)" ::: "memory");                         \
    __builtin_amdgcn_s_barrier();                                              \
  }

    for (int t = 0; t < T_STEPS; t += 2) {
        STEP(t,     0, PA0, PA1);
        STEP(t + 1, 1, PB0, PB1);
    }
#undef STEP

    // ---------------- epilogue: out = h_last @ W_out.T + b_out -------------
#pragma unroll
    for (int r = 0; r < 4; ++r) {
        const int b = l4 * 4 + r;
        const int j = q * 16 + l15;
        *(float*)(smem + 12288 + (b * 64 + j) * 4) = hl[r];
    }
    asm volatile("s_waitcnt lgkmcnt(0)" ::: "memory");
    __builtin_amdgcn_s_barrier();

    if (tid < 160) {
        const int b = tid / 10;
        const int o = tid - b * 10;
        const f32x4* hf = (const f32x4*)(smem + 12288 + b * 256);
        const f32x4* wr = (const f32x4*)(W_out + o * 64);
        float s = b_out[o];
#pragma unroll
        for (int j4 = 0; j4 < 16; ++j4) {
            f32x4 h4 = hf[j4];
            f32x4 w4 = wr[j4];
            s += h4[0] * w4[0] + h4[1] * w4[1] + h4[2] * w4[2] + h4[3] * w4[3];
        }
        out[(b0 + b) * 10 + o] = s;
    }
}

extern "C" void kernel_launch(void* const* d_in, const int* in_sizes, int n_in,
                              void* d_out, int out_size, void* d_ws, size_t ws_size,
                              hipStream_t stream) {
    const float* x     = (const float*)d_in[0];
    const float* W_ih  = (const float*)d_in[1];
    const float* W_hh  = (const float*)d_in[2];
    const float* b_ih  = (const float*)d_in[3];
    const float* b_hh  = (const float*)d_in[4];
    const float* W_out = (const float*)d_in[5];
    const float* b_out = (const float*)d_in[6];
    (void)in_sizes; (void)n_in; (void)out_size; (void)d_ws; (void)ws_size;

    lstm_fused_kernel<<<dim3(256), dim3(256), 0, stream>>>(
        x, W_ih, W_hh, b_ih, b_hh, W_out, b_out, (float*)d_out);
}

// Round 2
// 177.841 us; speedup vs baseline: 1.5290x; 1.5290x over previous
//
#include <hip/hip_runtime.h>

// Fused LSTM (B=4096, T=256, I=128, H=64) + projection (O=10).
// 256 WGs x 256 threads; WG owns 16 batch rows; wave q owns interleaved gate
// slice {64*nt + 16*q + col} so i/f/g/o for one (b,j) land in one lane.
// Weights in VGPRs. Pipelined: window t does h-MFMAs(t) -> [x-MFMAs(t+1) ||
// nonlin(t)] -> write h(t) -> barrier. x: 4-deep LDS ring + 4-window global
// prefetch (vmcnt never drained). rcp/exp via raw asm, bf16 via v_cvt_pk.

typedef __attribute__((ext_vector_type(8))) short bf16x8;
typedef __attribute__((ext_vector_type(4))) float f32x4;
typedef __attribute__((ext_vector_type(4))) int i32x4;

#define T_STEPS 256
#define L2E 1.44269504f

__device__ __forceinline__ short f2bf(float f) {           // prologue only
    unsigned u = __float_as_uint(f);
    u += 0x7FFFu + ((u >> 16) & 1u);
    return (short)(u >> 16);
}
__device__ __forceinline__ unsigned cvt_pk(float lo, float hi) {
    unsigned r;
    asm("v_cvt_pk_bf16_f32 %0, %1, %2" : "=v"(r) : "v"(lo), "v"(hi));
    return r;
}
__device__ __forceinline__ float frcp(float x) {
    float r; asm("v_rcp_f32 %0, %1" : "=v"(r) : "v"(x)); return r;
}
__device__ __forceinline__ float fexp2(float x) {
    float r; asm("v_exp_f32 %0, %1" : "=v"(r) : "v"(x)); return r;
}
__device__ __forceinline__ float sigm(float x) { return frcp(1.0f + fexp2(x * -L2E)); }
__device__ __forceinline__ float tanh_f(float x) { return 1.0f - 2.0f * frcp(1.0f + fexp2(x * (2.0f * L2E))); }

#define MF(A, Bf, C) (C) = __builtin_amdgcn_mfma_f32_16x16x32_bf16((A), (Bf), (C), 0, 0, 0)
#define PACK8(Av, Bv, W) { (W).x = cvt_pk((Av)[0], (Av)[1]); (W).y = cvt_pk((Av)[2], (Av)[3]); \
                           (W).z = cvt_pk((Bv)[0], (Bv)[1]); (W).w = cvt_pk((Bv)[2], (Bv)[3]); }

__global__ __launch_bounds__(256, 1) void lstm_fused_kernel(
    const float* __restrict__ x,
    const float* __restrict__ W_ih,
    const float* __restrict__ W_hh,
    const float* __restrict__ b_ih,
    const float* __restrict__ b_hh,
    const float* __restrict__ W_out,
    const float* __restrict__ b_out,
    float* __restrict__ out)
{
    // [0,16384): x ring, 4 x 4KB bf16 A-fragments
    // [16384,20480): h double buffer, 2 x 2KB bf16
    // [20480,24576): hf (final h, fp32)
    __shared__ __align__(16) char smem[24576];

    const int tid  = threadIdx.x;
    const int lane = tid & 63;
    const int q    = tid >> 6;
    const int l15  = lane & 15;
    const int l4   = lane >> 4;
    const int b0   = blockIdx.x * 16;

    // ---------------- weight fragments ----------------
    bf16x8 Bih[4][4];
    bf16x8 Bhh[4][2];
    f32x4  biasC[4];
#pragma unroll
    for (int nt = 0; nt < 4; ++nt) {
        const int row = nt * 64 + q * 16 + l15;
#pragma unroll
        for (int ks = 0; ks < 4; ++ks) {
            const float* p = W_ih + row * 128 + ks * 32 + l4 * 8;
            f32x4 a = *(const f32x4*)p;
            f32x4 b = *(const f32x4*)(p + 4);
            bf16x8 w;
#pragma unroll
            for (int j = 0; j < 4; ++j) { w[j] = f2bf(a[j]); w[4 + j] = f2bf(b[j]); }
            Bih[nt][ks] = w;
        }
#pragma unroll
        for (int ks = 0; ks < 2; ++ks) {
            const float* p = W_hh + row * 64 + ks * 32 + l4 * 8;
            f32x4 a = *(const f32x4*)p;
            f32x4 b = *(const f32x4*)(p + 4);
            bf16x8 w;
#pragma unroll
            for (int j = 0; j < 4; ++j) { w[j] = f2bf(a[j]); w[4 + j] = f2bf(b[j]); }
            Bhh[nt][ks] = w;
        }
        const float bb = b_ih[row] + b_hh[row];
        biasC[nt] = (f32x4){bb, bb, bb, bb};
    }

    // ---------------- staging / fragment address maps ----------------
    const int sc  = tid & 15;
    const int sb  = tid >> 4;
    const int sks = sc >> 2;
    const int schunk = ((sc & 3) << 4) | sb;
    const int xf_wr  = (((sks * 64 + schunk) * 16) ^ ((sks & 3) << 6));
    const float* xrow = x + (size_t)(b0 + sb) * T_STEPS * 128 + sc * 8;

    int xf_rd[4];
#pragma unroll
    for (int ks = 0; ks < 4; ++ks)
        xf_rd[ks] = (((ks * 64 + lane) * 16) ^ ((ks & 3) << 6));

    int hb_wr[4];
#pragma unroll
    for (int r = 0; r < 4; ++r) {
        const int b = l4 * 4 + r;
        const int j = q * 16 + l15;
        hb_wr[r] = ((b * 128 + j * 2) ^ ((b & 7) << 4) ^ ((b >> 3) << 5));
    }
    int hb_rd[2];
#pragma unroll
    for (int ks = 0; ks < 2; ++ks)
        hb_rd[ks] = ((l15 * 128 + ks * 64 + l4 * 16) ^ ((l15 & 7) << 4) ^ ((l15 >> 3) << 5));

    // ---------------- prologue ----------------
    // stage x(0),x(1),x(2) into xbuf 0,1,2
#pragma unroll
    for (int s = 0; s < 3; ++s) {
        f32x4 a = *(const f32x4*)(xrow + (size_t)s * 128);
        f32x4 b = *(const f32x4*)(xrow + (size_t)s * 128 + 4);
        i32x4 w; PACK8(a, b, w);
        *(i32x4*)(smem + s * 4096 + xf_wr) = w;
    }
    // prefetch regs: P[s] = x(3+s)
    f32x4 P0_[4], P1_[4];
#pragma unroll
    for (int s = 0; s < 4; ++s) {
        P0_[s] = *(const f32x4*)(xrow + (size_t)(s + 3) * 128);
        P1_[s] = *(const f32x4*)(xrow + (size_t)(s + 3) * 128 + 4);
    }
    ((unsigned long long*)(smem + 16384 + 2048))[tid] = 0ull;  // h(-1) = 0

    asm volatile("s_waitcnt lgkmcnt(0)" ::: "memory");
    __builtin_amdgcn_s_barrier();

    float c[4]  = {0.f, 0.f, 0.f, 0.f};
    float hl[4] = {0.f, 0.f, 0.f, 0.f};

    // accA = bias + gx(0)
    f32x4 accA[4], accB[4];
    {
        bf16x8 Ax0 = *(const bf16x8*)(smem + xf_rd[0]);
        bf16x8 Ax1 = *(const bf16x8*)(smem + xf_rd[1]);
        bf16x8 Ax2 = *(const bf16x8*)(smem + xf_rd[2]);
        bf16x8 Ax3 = *(const bf16x8*)(smem + xf_rd[3]);
#pragma unroll
        for (int nt = 0; nt < 4; ++nt) accA[nt] = biasC[nt];
        MF(Ax0, Bih[0][0], accA[0]); MF(Ax0, Bih[1][0], accA[1]);
        MF(Ax0, Bih[2][0], accA[2]); MF(Ax0, Bih[3][0], accA[3]);
        MF(Ax1, Bih[0][1], accA[0]); MF(Ax1, Bih[1][1], accA[1]);
        MF(Ax1, Bih[2][1], accA[2]); MF(Ax1, Bih[3][1], accA[3]);
        MF(Ax2, Bih[0][2], accA[0]); MF(Ax2, Bih[1][2], accA[1]);
        MF(Ax2, Bih[2][2], accA[2]); MF(Ax2, Bih[3][2], accA[3]);
        MF(Ax3, Bih[0][3], accA[0]); MF(Ax3, Bih[1][3], accA[1]);
        MF(Ax3, Bih[2][3], accA[2]); MF(Ax3, Bih[3][3], accA[3]);
    }

    // Window tt: h-MFMAs complete gates(tt) in ACUR; ANXT = bias + gx(tt+1);
    // stage x(tt+3) from P[tt&3], issue load x(tt+7); nonlin(tt) -> h write.
#define WINDOW(tt, T4, ACUR, ANXT)                                             \
  {                                                                            \
    const char* hbR = smem + 16384 + ((((T4) & 1) ^ 1) * 2048);                \
    char*       hbW = smem + 16384 + (((T4) & 1) * 2048);                      \
    const char* xfb = smem + ((((T4) + 1) & 3) * 4096);                        \
    char*       xfw = smem + ((((T4) + 3) & 3) * 4096);                        \
    bf16x8 Ah0 = *(const bf16x8*)(hbR + hb_rd[0]);                             \
    bf16x8 Ah1 = *(const bf16x8*)(hbR + hb_rd[1]);                             \
    MF(Ah0, Bhh[0][0], ACUR[0]); MF(Ah0, Bhh[1][0], ACUR[1]);                  \
    MF(Ah0, Bhh[2][0], ACUR[2]); MF(Ah0, Bhh[3][0], ACUR[3]);                  \
    MF(Ah1, Bhh[0][1], ACUR[0]); MF(Ah1, Bhh[1][1], ACUR[1]);                  \
    MF(Ah1, Bhh[2][1], ACUR[2]); MF(Ah1, Bhh[3][1], ACUR[3]);                  \
    bf16x8 Ax0 = *(const bf16x8*)(xfb + xf_rd[0]);                             \
    bf16x8 Ax1 = *(const bf16x8*)(xfb + xf_rd[1]);                             \
    bf16x8 Ax2 = *(const bf16x8*)(xfb + xf_rd[2]);                             \
    bf16x8 Ax3 = *(const bf16x8*)(xfb + xf_rd[3]);                             \
    ANXT[0] = biasC[0]; ANXT[1] = biasC[1];                                    \
    ANXT[2] = biasC[2]; ANXT[3] = biasC[3];                                    \
    MF(Ax0, Bih[0][0], ANXT[0]); MF(Ax0, Bih[1][0], ANXT[1]);                  \
    MF(Ax0, Bih[2][0], ANXT[2]); MF(Ax0, Bih[3][0], ANXT[3]);                  \
    MF(Ax1, Bih[0][1], ANXT[0]); MF(Ax1, Bih[1][1], ANXT[1]);                  \
    MF(Ax1, Bih[2][1], ANXT[2]); MF(Ax1, Bih[3][1], ANXT[3]);                  \
    MF(Ax2, Bih[0][2], ANXT[0]); MF(Ax2, Bih[1][2], ANXT[1]);                  \
    MF(Ax2, Bih[2][2], ANXT[2]); MF(Ax2, Bih[3][2], ANXT[3]);                  \
    MF(Ax3, Bih[0][3], ANXT[0]); MF(Ax3, Bih[1][3], ANXT[1]);                  \
    MF(Ax3, Bih[2][3], ANXT[2]); MF(Ax3, Bih[3][3], ANXT[3]);                  \
    {                                                                          \
      i32x4 w; PACK8(P0_[(T4)], P1_[(T4)], w);                                 \
      *(i32x4*)(xfw + xf_wr) = w;                                              \
      int tc = (tt) + 7; tc = tc > 255 ? 255 : tc;                             \
      P0_[(T4)] = *(const f32x4*)(xrow + (size_t)tc * 128);                    \
      P1_[(T4)] = *(const f32x4*)(xrow + (size_t)tc * 128 + 4);                \
    }                                                                          \
    _Pragma("unroll")                                                          \
    for (int r = 0; r < 4; ++r) {                                              \
      float iv = sigm(ACUR[0][r]);                                             \
      float fv = sigm(ACUR[1][r]);                                             \
      float gv = tanh_f(ACUR[2][r]);                                           \
      float ov = sigm(ACUR[3][r]);                                             \
      float cc = fv * c[r] + iv * gv;                                          \
      c[r] = cc;                                                               \
      hl[r] = ov * tanh_f(cc);                                                 \
    }                                                                          \
    {                                                                          \
      unsigned w01 = cvt_pk(hl[0], hl[1]);                                     \
      unsigned w23 = cvt_pk(hl[2], hl[3]);                                     \
      *(short*)(hbW + hb_wr[0]) = (short)w01;                                  \
      *(short*)(hbW + hb_wr[1]) = (short)(w01 >> 16);                          \
      *(short*)(hbW + hb_wr[2]) = (short)w23;                                  \
      *(short*)(hbW + hb_wr[3]) = (short)(w23 >> 16);                          \
    }                                                                          \
    asm volatile("s_waitcnt lgkmcnt(0)" ::: "memory");                         \
    __builtin_amdgcn_s_barrier();                                              \
  }

    for (int t = 0; t < T_STEPS; t += 4) {
        WINDOW(t,     0, accA, accB);
        WINDOW(t + 1, 1, accB, accA);
        WINDOW(t + 2, 2, accA, accB);
        WINDOW(t + 3, 3, accB, accA);
    }
#undef WINDOW

    // ---------------- epilogue: out = h_last @ W_out.T + b_out -------------
#pragma unroll
    for (int r = 0; r < 4; ++r) {
        const int b = l4 * 4 + r;
        const int j = q * 16 + l15;
        *(float*)(smem + 20480 + (b * 64 + j) * 4) = hl[r];
    }
    asm volatile("s_waitcnt lgkmcnt(0)" ::: "memory");
    __builtin_amdgcn_s_barrier();

    if (tid < 160) {
        const int b = tid / 10;
        const int o = tid - b * 10;
        const f32x4* hf = (const f32x4*)(smem + 20480 + b * 256);
        const f32x4* wr = (const f32x4*)(W_out + o * 64);
        float s = b_out[o];
#pragma unroll
        for (int j4 = 0; j4 < 16; ++j4) {
            f32x4 h4 = hf[j4];
            f32x4 w4 = wr[j4];
            s += h4[0] * w4[0] + h4[1] * w4[1] + h4[2] * w4[2] + h4[3] * w4[3];
        }
        out[(b0 + b) * 10 + o] = s;
    }
}

extern "C" void kernel_launch(void* const* d_in, const int* in_sizes, int n_in,
                              void* d_out, int out_size, void* d_ws, size_t ws_size,
                              hipStream_t stream) {
    const float* x     = (const float*)d_in[0];
    const float* W_ih  = (const float*)d_in[1];
    const float* W_hh  = (const float*)d_in[2];
    const float* b_ih  = (const float*)d_in[3];
    const float* b_hh  = (const float*)d_in[4];
    const float* W_out = (const float*)d_in[5];
    const float* b_out = (const float*)d_in[6];
    (void)in_sizes; (void)n_in; (void)out_size; (void)d_ws; (void)ws_size;

    lstm_fused_kernel<<<dim3(256), dim3(256), 0, stream>>>(
        x, W_ih, W_hh, b_ih, b_hh, W_out, b_out, (float*)d_out);
}